// Round 2
// baseline (2185.369 us; speedup 1.0000x reference)
//
#include <hip/hip_runtime.h>
#include <hip/hip_bf16.h>

// RNNClassifier: B=64, T=2048, V=50000, E=256, H=256, O=16
// K1 (MFMA f16): xh16[B*T][H] = fp16( emb[x] @ W_ih^T + b_ih + b_hh )
// K2 (MFMA f16): h_t = tanh(xh_t + W_hh @ h_{t-1}) scanned; one WG per batch
//   chain, wave w owns output rows [32w,32w+32) for ALL K (no cross-wave
//   reduce), W_hh as A-fragments in VGPRs, h ping-pongs in LDS as fp16,
//   1 barrier/step. MLP head fused in K2 epilogue.

#define B_  64
#define T_  2048
#define E_  256
#define H_  256
#define O_  16
#define H2_ 128

typedef _Float16 f16x4 __attribute__((ext_vector_type(4)));
typedef _Float16 f16x8 __attribute__((ext_vector_type(8)));
typedef float    f32x4 __attribute__((ext_vector_type(4)));

__device__ __forceinline__ float tanh_fast(float x) {
  // tanh(x) = 1 - 2/(exp(2x)+1); exact at +/-inf
  return 1.0f - 2.0f / (__expf(2.0f * x) + 1.0f);
}

// ---------------------------------------------------------------------------
// K1: gathered GEMM via MFMA. Grid = B*T/64 WGs x 256 thr (4 waves).
// A = 64 gathered emb rows (fp16 in LDS, +8 pad), B-frags = W_ih in VGPRs
// (wave w covers n in [64w,64w+64)). C written as fp16 xh with bias.
// MFMA layouts (m89/m120-verified): A[m=lane&15][k=(lane>>4)*8+j],
// B[k=(lane>>4)*8+j][n=lane&15], C[row=(lane>>4)*4+reg][col=lane&15].
// ---------------------------------------------------------------------------
__global__ __launch_bounds__(256) void k1_xh(
    const int* __restrict__ x, const float* __restrict__ emb,
    const float* __restrict__ W_ih, const float* __restrict__ b_ih,
    const float* __restrict__ b_hh, _Float16* __restrict__ xh) {
  __shared__ _Float16 A16[64][264];  // +8 halves: rows stay 16B-aligned (528B), banks spread
  const int tid  = threadIdx.x;
  const int w    = tid >> 6;         // wave 0..3
  const int lane = tid & 63;
  const int nl   = lane & 15;
  const int koff = (lane >> 4) << 3; // 0,8,16,24
  const long r0  = (long)blockIdx.x * 64;

  // stage 64 gathered emb rows -> fp16 LDS (coalesced: 64 lanes span one row)
  {
    const int c4 = lane << 2;  // 0..252
#pragma unroll
    for (int it = 0; it < 16; ++it) {
      const int row = (it << 2) + w;
      const long tok = x[r0 + row];
      const float4 v = *(const float4*)&emb[tok * E_ + c4];
      f16x4 hv;
      hv[0] = (_Float16)v.x; hv[1] = (_Float16)v.y;
      hv[2] = (_Float16)v.z; hv[3] = (_Float16)v.w;
      *(f16x4*)&A16[row][c4] = hv;
    }
  }

  // B-fragments: W_ih rows n = 64w + nt*16 + nl, 8 consecutive k per lane
  f16x8 bfr[4][8];
#pragma unroll
  for (int nt = 0; nt < 4; ++nt) {
    const int n = (w << 6) + (nt << 4) + nl;
#pragma unroll
    for (int kt = 0; kt < 8; ++kt) {
      const int k0 = (kt << 5) + koff;
      const float4 u0 = *(const float4*)&W_ih[n * E_ + k0];
      const float4 u1 = *(const float4*)&W_ih[n * E_ + k0 + 4];
      f16x8 bv;
      bv[0] = (_Float16)u0.x; bv[1] = (_Float16)u0.y;
      bv[2] = (_Float16)u0.z; bv[3] = (_Float16)u0.w;
      bv[4] = (_Float16)u1.x; bv[5] = (_Float16)u1.y;
      bv[6] = (_Float16)u1.z; bv[7] = (_Float16)u1.w;
      bfr[nt][kt] = bv;
    }
  }
  __syncthreads();

  f32x4 acc[4][4];
#pragma unroll
  for (int mt = 0; mt < 4; ++mt)
#pragma unroll
    for (int nt = 0; nt < 4; ++nt) acc[mt][nt] = (f32x4){};

#pragma unroll
  for (int mt = 0; mt < 4; ++mt) {
#pragma unroll
    for (int kt = 0; kt < 8; ++kt) {
      const f16x8 a = *(const f16x8*)&A16[(mt << 4) + nl][(kt << 5) + koff];
#pragma unroll
      for (int nt = 0; nt < 4; ++nt)
        acc[mt][nt] = __builtin_amdgcn_mfma_f32_16x16x32_f16(a, bfr[nt][kt], acc[mt][nt], 0, 0, 0);
    }
  }

  // epilogue: + (b_ih+b_hh), store fp16
  const int rsub = (lane >> 4) << 2;  // 0,4,8,12
#pragma unroll
  for (int nt = 0; nt < 4; ++nt) {
    const int n = (w << 6) + (nt << 4) + nl;
    const float bias = b_ih[n] + b_hh[n];
#pragma unroll
    for (int mt = 0; mt < 4; ++mt) {
#pragma unroll
      for (int j = 0; j < 4; ++j) {
        const long r = r0 + (mt << 4) + rsub + j;
        xh[r * H_ + n] = (_Float16)(acc[mt][nt][j] + bias);
      }
    }
  }
}

// ---------------------------------------------------------------------------
// K2: scan via MFMA matvec (B-operand = h in column 0 only). Grid = 64 WGs
// (one per chain) x 512 thr (8 waves). Wave w: rows [32w,32w+32) = 2 M-tiles,
// all 8 K-tiles -> 16 MFMA/step, no cross-wave reduce, 1 barrier/step.
// ---------------------------------------------------------------------------
__global__ __launch_bounds__(512) void k2_rnn(
    const _Float16* __restrict__ xh, const float* __restrict__ W_hh,
    const float* __restrict__ fc1_w, const float* __restrict__ fc1_b,
    const float* __restrict__ fc2_w, const float* __restrict__ fc2_b,
    float* __restrict__ out) {
  __shared__ _Float16 h16[2][H_];    // ping-pong fp16 hidden state
  __shared__ float hid_s[H2_];

  const int tid  = threadIdx.x;
  const int w    = tid >> 6;         // wave 0..7
  const int lane = tid & 63;
  const int nl   = lane & 15;
  const int quad = lane >> 4;        // 0..3
  const int koff = quad << 3;
  const bool act = (nl == 0);        // col-0 lanes hold B data and C results
  const int rb0  = (w << 5) + (quad << 2);  // C rows for mt=0 (4 consecutive via reg)
  const int b    = blockIdx.x;

  // A-fragments: W_hh rows [32w..32w+32), fp32->fp16, 64 VGPRs/lane, loaded once
  f16x8 afr[2][8];
#pragma unroll
  for (int mt = 0; mt < 2; ++mt) {
    const int i = (w << 5) + (mt << 4) + nl;
#pragma unroll
    for (int kt = 0; kt < 8; ++kt) {
      const int k0 = (kt << 5) + koff;
      const float4 u0 = *(const float4*)&W_hh[i * H_ + k0];
      const float4 u1 = *(const float4*)&W_hh[i * H_ + k0 + 4];
      f16x8 av;
      av[0] = (_Float16)u0.x; av[1] = (_Float16)u0.y;
      av[2] = (_Float16)u0.z; av[3] = (_Float16)u0.w;
      av[4] = (_Float16)u1.x; av[5] = (_Float16)u1.y;
      av[6] = (_Float16)u1.z; av[7] = (_Float16)u1.w;
      afr[mt][kt] = av;
    }
  }

  if (tid < 64) {  // h0 = 0
    f16x4 zz = {};
    *(f16x4*)&h16[0][tid << 2] = zz;
  }

  // xh prefetch (active lanes): 4+4 rows per lane, one step ahead
  const size_t xbase = (size_t)b * T_ * H_;
  f16x4 xv0 = {}, xv1 = {};
  if (act) {
    xv0 = *(const f16x4*)&xh[xbase + rb0];
    xv1 = *(const f16x4*)&xh[xbase + rb0 + 16];
  }
  __syncthreads();

  for (int t = 0; t < T_; ++t) {
    const int cur = t & 1;

    // prefetch next step's xh while MFMAs run
    f16x4 nx0 = {}, nx1 = {};
    if (act && t + 1 < T_) {
      const size_t p = xbase + (size_t)(t + 1) * H_ + rb0;
      nx0 = *(const f16x4*)&xh[p];
      nx1 = *(const f16x4*)&xh[p + 16];
    }

    // B-fragments: h in column n=0 -> only lanes {0,16,32,48} load (8 halves each)
    f16x8 bfr[8];
#pragma unroll
    for (int kt = 0; kt < 8; ++kt) {
      f16x8 z = {};
      if (act) z = *(const f16x8*)&h16[cur][(kt << 5) + koff];
      bfr[kt] = z;
    }

    const f32x4 zero = {};
    f32x4 acc0 = __builtin_amdgcn_mfma_f32_16x16x32_f16(afr[0][0], bfr[0], zero, 0, 0, 0);
    f32x4 acc1 = __builtin_amdgcn_mfma_f32_16x16x32_f16(afr[1][0], bfr[0], zero, 0, 0, 0);
#pragma unroll
    for (int kt = 1; kt < 8; ++kt) {
      acc0 = __builtin_amdgcn_mfma_f32_16x16x32_f16(afr[0][kt], bfr[kt], acc0, 0, 0, 0);
      acc1 = __builtin_amdgcn_mfma_f32_16x16x32_f16(afr[1][kt], bfr[kt], acc1, 0, 0, 0);
    }

    if (act) {  // col 0 of C: rows rb0+j (mt=0), rb0+16+j (mt=1)
      const int nxt = cur ^ 1;
      f16x4 o0, o1;
#pragma unroll
      for (int j = 0; j < 4; ++j) {
        o0[j] = (_Float16)tanh_fast(acc0[j] + (float)xv0[j]);
        o1[j] = (_Float16)tanh_fast(acc1[j] + (float)xv1[j]);
      }
      *(f16x4*)&h16[nxt][rb0]      = o0;
      *(f16x4*)&h16[nxt][rb0 + 16] = o1;
    }
    xv0 = nx0; xv1 = nx1;
    __syncthreads();
  }

  // fused MLP head; last write went to h16[0] (t=2047 writes nxt=0)
  if (tid < H2_) {
    float s = fc1_b[tid];
#pragma unroll 8
    for (int k = 0; k < H_; ++k) s += fc1_w[tid * H_ + k] * (float)h16[0][k];
    hid_s[tid] = fmaxf(s, 0.f);
  }
  __syncthreads();
  if (tid < O_) {
    float s = fc2_b[tid];
#pragma unroll 8
    for (int k = 0; k < H2_; ++k) s += fc2_w[tid * H2_ + k] * hid_s[k];
    out[b * O_ + tid] = s;
  }
}

extern "C" void kernel_launch(void* const* d_in, const int* in_sizes, int n_in,
                              void* d_out, int out_size, void* d_ws, size_t ws_size,
                              hipStream_t stream) {
  const int*   x     = (const int*)d_in[0];
  const float* emb   = (const float*)d_in[1];
  const float* W_ih  = (const float*)d_in[2];
  const float* W_hh  = (const float*)d_in[3];
  const float* b_ih  = (const float*)d_in[4];
  const float* b_hh  = (const float*)d_in[5];
  const float* fc1_w = (const float*)d_in[6];
  const float* fc1_b = (const float*)d_in[7];
  const float* fc2_w = (const float*)d_in[8];
  const float* fc2_b = (const float*)d_in[9];
  float* outp = (float*)d_out;

  _Float16* xh16 = (_Float16*)d_ws;  // 64 MiB (ws verified >= 128 MiB in R1)

  k1_xh<<<dim3(B_ * T_ / 64), dim3(256), 0, stream>>>(x, emb, W_ih, b_ih, b_hh, xh16);
  k2_rnn<<<dim3(B_), dim3(512), 0, stream>>>(xh16, W_hh, fc1_w, fc1_b, fc2_w, fc2_b, outp);
}

// Round 3
// 2020.188 us; speedup vs baseline: 1.0818x; 1.0818x over previous
//
#include <hip/hip_runtime.h>
#include <hip/hip_bf16.h>

// RNNClassifier: B=64, T=2048, V=50000, E=256, H=256, O=16
// K1 (MFMA f16): xh16[B*T][H] = fp16( emb[x] @ W_ih^T + b_ih + b_hh )
// K2 (MFMA f16): 16 chains per WG batched into the 16 B-columns of
//   mfma_f32_16x16x32_f16. Grid = 4 WGs x 8 waves; wave w owns output rows
//   [32w,32w+32) for all K (no cross-wave reduce) -> 16 MFMA/wave/step for
//   16 chains. W_hh A-frags in VGPRs (64/lane), h ping-pongs in LDS
//   chain-major [16][264], 1 barrier/step, xh prefetch distance 2.

#define B_  64
#define T_  2048
#define E_  256
#define H_  256
#define O_  16
#define H2_ 128
#define CH  16    // chains per WG
#define HP  264   // padded per-chain h stride in halves (528 B)

typedef _Float16 f16x4 __attribute__((ext_vector_type(4)));
typedef _Float16 f16x8 __attribute__((ext_vector_type(8)));
typedef float    f32x4 __attribute__((ext_vector_type(4)));

__device__ __forceinline__ float tanh_fast(float x) {
  return 1.0f - 2.0f / (__expf(2.0f * x) + 1.0f);  // exact at +/-inf
}

// ---------------------------------------------------------------------------
// K1: gathered GEMM via MFMA (unchanged from R2 — passed, small cost).
// ---------------------------------------------------------------------------
__global__ __launch_bounds__(256) void k1_xh(
    const int* __restrict__ x, const float* __restrict__ emb,
    const float* __restrict__ W_ih, const float* __restrict__ b_ih,
    const float* __restrict__ b_hh, _Float16* __restrict__ xh) {
  __shared__ _Float16 A16[64][264];
  const int tid  = threadIdx.x;
  const int w    = tid >> 6;
  const int lane = tid & 63;
  const int nl   = lane & 15;
  const int koff = (lane >> 4) << 3;
  const long r0  = (long)blockIdx.x * 64;

  {
    const int c4 = lane << 2;
#pragma unroll
    for (int it = 0; it < 16; ++it) {
      const int row = (it << 2) + w;
      const long tok = x[r0 + row];
      const float4 v = *(const float4*)&emb[tok * E_ + c4];
      f16x4 hv;
      hv[0] = (_Float16)v.x; hv[1] = (_Float16)v.y;
      hv[2] = (_Float16)v.z; hv[3] = (_Float16)v.w;
      *(f16x4*)&A16[row][c4] = hv;
    }
  }

  f16x8 bfr[4][8];
#pragma unroll
  for (int nt = 0; nt < 4; ++nt) {
    const int n = (w << 6) + (nt << 4) + nl;
#pragma unroll
    for (int kt = 0; kt < 8; ++kt) {
      const int k0 = (kt << 5) + koff;
      const float4 u0 = *(const float4*)&W_ih[n * E_ + k0];
      const float4 u1 = *(const float4*)&W_ih[n * E_ + k0 + 4];
      f16x8 bv;
      bv[0] = (_Float16)u0.x; bv[1] = (_Float16)u0.y;
      bv[2] = (_Float16)u0.z; bv[3] = (_Float16)u0.w;
      bv[4] = (_Float16)u1.x; bv[5] = (_Float16)u1.y;
      bv[6] = (_Float16)u1.z; bv[7] = (_Float16)u1.w;
      bfr[nt][kt] = bv;
    }
  }
  __syncthreads();

  f32x4 acc[4][4];
#pragma unroll
  for (int mt = 0; mt < 4; ++mt)
#pragma unroll
    for (int nt = 0; nt < 4; ++nt) acc[mt][nt] = (f32x4){};

#pragma unroll
  for (int mt = 0; mt < 4; ++mt) {
#pragma unroll
    for (int kt = 0; kt < 8; ++kt) {
      const f16x8 a = *(const f16x8*)&A16[(mt << 4) + nl][(kt << 5) + koff];
#pragma unroll
      for (int nt = 0; nt < 4; ++nt)
        acc[mt][nt] = __builtin_amdgcn_mfma_f32_16x16x32_f16(a, bfr[nt][kt], acc[mt][nt], 0, 0, 0);
    }
  }

  const int rsub = (lane >> 4) << 2;
#pragma unroll
  for (int nt = 0; nt < 4; ++nt) {
    const int n = (w << 6) + (nt << 4) + nl;
    const float bias = b_ih[n] + b_hh[n];
#pragma unroll
    for (int mt = 0; mt < 4; ++mt) {
#pragma unroll
      for (int j = 0; j < 4; ++j) {
        const long r = r0 + (mt << 4) + rsub + j;
        xh[r * H_ + n] = (_Float16)(acc[mt][nt][j] + bias);
      }
    }
  }
}

// ---------------------------------------------------------------------------
// K2: 16-chain batched scan. Lane (quad=lane>>4, nl=lane&15): chain = nl,
// C rows rb..rb+3 (mt=0) and rb+16..rb+19 (mt=1), rb = 32w + 4*quad.
// B-frag: lane reads h16[cur][nl][32kt + 8quad .. +8]  (ds_read_b128).
// ---------------------------------------------------------------------------
__global__ __launch_bounds__(512) void k2_rnn(
    const _Float16* __restrict__ xh, const float* __restrict__ W_hh,
    const float* __restrict__ fc1_w, const float* __restrict__ fc1_b,
    const float* __restrict__ fc2_w, const float* __restrict__ fc2_b,
    float* __restrict__ out) {
  __shared__ _Float16 h16[2][CH][HP];     // ping-pong, chain-major, padded
  __shared__ float hid_s[CH][H2_ + 4];

  const int tid  = threadIdx.x;
  const int w    = tid >> 6;
  const int lane = tid & 63;
  const int nl   = lane & 15;              // chain index within WG
  const int quad = lane >> 4;
  const int koff = quad << 3;
  const int rb   = (w << 5) + (quad << 2); // C rows (mt=0); mt=1 at +16
  const int c0   = blockIdx.x * CH;

  // A-fragments: W_hh rows [32w,32w+32), fp32->fp16, loaded once (64 VGPR)
  f16x8 afr[2][8];
#pragma unroll
  for (int mt = 0; mt < 2; ++mt) {
    const int i = (w << 5) + (mt << 4) + nl;
#pragma unroll
    for (int kt = 0; kt < 8; ++kt) {
      const int k0 = (kt << 5) + koff;
      const float4 u0 = *(const float4*)&W_hh[i * H_ + k0];
      const float4 u1 = *(const float4*)&W_hh[i * H_ + k0 + 4];
      f16x8 av;
      av[0] = (_Float16)u0.x; av[1] = (_Float16)u0.y;
      av[2] = (_Float16)u0.z; av[3] = (_Float16)u0.w;
      av[4] = (_Float16)u1.x; av[5] = (_Float16)u1.y;
      av[6] = (_Float16)u1.z; av[7] = (_Float16)u1.w;
      afr[mt][kt] = av;
    }
  }

  // h0 = 0 (k<256 only; pad never read)
  { *(f16x8*)&h16[0][tid >> 5][(tid & 31) << 3] = (f16x8){}; }

  // xh base for this lane: chain c0+nl, rows rb / rb+16
  const _Float16* xb = xh + (size_t)(c0 + nl) * (T_ * H_) + rb;

  // prefetch t=0 and t=1
  f16x4 xe0 = *(const f16x4*)&xb[0];
  f16x4 xe1 = *(const f16x4*)&xb[16];
  f16x4 xo0 = *(const f16x4*)&xb[H_];
  f16x4 xo1 = *(const f16x4*)&xb[H_ + 16];
  __syncthreads();

  for (int t = 0; t < T_; t += 2) {
    // prefetch t+2 (clamped; tail values unused)
    const size_t pn = (size_t)(t + 2 < T_ ? t + 2 : t) * H_;
    f16x4 ne0 = *(const f16x4*)&xb[pn];
    f16x4 ne1 = *(const f16x4*)&xb[pn + 16];

    {  // even step: read h16[0], write h16[1]
      f16x8 bfr[8];
#pragma unroll
      for (int kt = 0; kt < 8; ++kt)
        bfr[kt] = *(const f16x8*)&h16[0][nl][(kt << 5) + koff];
      f32x4 a0l = {}, a0h = {}, a1l = {}, a1h = {};
#pragma unroll
      for (int kt = 0; kt < 4; ++kt) {
        a0l = __builtin_amdgcn_mfma_f32_16x16x32_f16(afr[0][kt], bfr[kt], a0l, 0, 0, 0);
        a1l = __builtin_amdgcn_mfma_f32_16x16x32_f16(afr[1][kt], bfr[kt], a1l, 0, 0, 0);
      }
#pragma unroll
      for (int kt = 4; kt < 8; ++kt) {
        a0h = __builtin_amdgcn_mfma_f32_16x16x32_f16(afr[0][kt], bfr[kt], a0h, 0, 0, 0);
        a1h = __builtin_amdgcn_mfma_f32_16x16x32_f16(afr[1][kt], bfr[kt], a1h, 0, 0, 0);
      }
      const f32x4 s0 = a0l + a0h, s1 = a1l + a1h;
      f16x4 o0, o1;
#pragma unroll
      for (int j = 0; j < 4; ++j) {
        o0[j] = (_Float16)tanh_fast(s0[j] + (float)xe0[j]);
        o1[j] = (_Float16)tanh_fast(s1[j] + (float)xe1[j]);
      }
      *(f16x4*)&h16[1][nl][rb]      = o0;
      *(f16x4*)&h16[1][nl][rb + 16] = o1;
      __syncthreads();
    }

    // prefetch t+3 (clamped)
    const size_t po = (size_t)(t + 3 < T_ ? t + 3 : t) * H_;
    f16x4 no0 = *(const f16x4*)&xb[po];
    f16x4 no1 = *(const f16x4*)&xb[po + 16];

    {  // odd step: read h16[1], write h16[0]
      f16x8 bfr[8];
#pragma unroll
      for (int kt = 0; kt < 8; ++kt)
        bfr[kt] = *(const f16x8*)&h16[1][nl][(kt << 5) + koff];
      f32x4 a0l = {}, a0h = {}, a1l = {}, a1h = {};
#pragma unroll
      for (int kt = 0; kt < 4; ++kt) {
        a0l = __builtin_amdgcn_mfma_f32_16x16x32_f16(afr[0][kt], bfr[kt], a0l, 0, 0, 0);
        a1l = __builtin_amdgcn_mfma_f32_16x16x32_f16(afr[1][kt], bfr[kt], a1l, 0, 0, 0);
      }
#pragma unroll
      for (int kt = 4; kt < 8; ++kt) {
        a0h = __builtin_amdgcn_mfma_f32_16x16x32_f16(afr[0][kt], bfr[kt], a0h, 0, 0, 0);
        a1h = __builtin_amdgcn_mfma_f32_16x16x32_f16(afr[1][kt], bfr[kt], a1h, 0, 0, 0);
      }
      const f32x4 s0 = a0l + a0h, s1 = a1l + a1h;
      f16x4 o0, o1;
#pragma unroll
      for (int j = 0; j < 4; ++j) {
        o0[j] = (_Float16)tanh_fast(s0[j] + (float)xo0[j]);
        o1[j] = (_Float16)tanh_fast(s1[j] + (float)xo1[j]);
      }
      *(f16x4*)&h16[0][nl][rb]      = o0;
      *(f16x4*)&h16[0][nl][rb + 16] = o1;
      __syncthreads();
    }

    xe0 = ne0; xe1 = ne1; xo0 = no0; xo1 = no1;
  }

  // MLP head for 16 chains; final h in h16[0] (T even)
#pragma unroll
  for (int p = 0; p < 4; ++p) {
    const int c = (tid >> 7) + (p << 2);
    const int o = tid & 127;
    float s = fc1_b[o];
#pragma unroll 8
    for (int k = 0; k < H_; ++k) s += fc1_w[o * H_ + k] * (float)h16[0][c][k];
    hid_s[c][o] = fmaxf(s, 0.f);
  }
  __syncthreads();
  if (tid < CH * O_) {
    const int c = tid >> 4, o = tid & 15;
    float s = fc2_b[o];
#pragma unroll 8
    for (int k = 0; k < H2_; ++k) s += fc2_w[o * H2_ + k] * hid_s[c][k];
    out[(size_t)(c0 + c) * O_ + o] = s;
  }
}

extern "C" void kernel_launch(void* const* d_in, const int* in_sizes, int n_in,
                              void* d_out, int out_size, void* d_ws, size_t ws_size,
                              hipStream_t stream) {
  const int*   x     = (const int*)d_in[0];
  const float* emb   = (const float*)d_in[1];
  const float* W_ih  = (const float*)d_in[2];
  const float* W_hh  = (const float*)d_in[3];
  const float* b_ih  = (const float*)d_in[4];
  const float* b_hh  = (const float*)d_in[5];
  const float* fc1_w = (const float*)d_in[6];
  const float* fc1_b = (const float*)d_in[7];
  const float* fc2_w = (const float*)d_in[8];
  const float* fc2_b = (const float*)d_in[9];
  float* outp = (float*)d_out;

  _Float16* xh16 = (_Float16*)d_ws;  // 64 MiB

  k1_xh<<<dim3(B_ * T_ / 64), dim3(256), 0, stream>>>(x, emb, W_ih, b_ih, b_hh, xh16);
  k2_rnn<<<dim3(B_ / CH), dim3(512), 0, stream>>>(xh16, W_hh, fc1_w, fc1_b, fc2_w, fc2_b, outp);
}

// Round 4
// 1769.580 us; speedup vs baseline: 1.2350x; 1.1416x over previous
//
#include <hip/hip_runtime.h>
#include <hip/hip_bf16.h>

// RNNClassifier: B=64, T=2048, V=50000, E=256, H=256, O=16
// K1 (MFMA f16): xh16[B*T][H] = fp16( emb[x] @ W_ih^T + b_ih + b_hh ),
//   C round-trips through LDS for coalesced 16B stores.
// K2 (MFMA f16): 16 chains batched into B-columns; 4 WGs x 8 waves; wave w
//   owns rows [32w,32w+32). W_hh A-frags in VGPRs. h ping-pongs in LDS.
//   Key R4 change: raw "lgkmcnt-only" barrier (no vmcnt(0) drain) so xh
//   prefetches (distance 4) stay in flight across steps; xh folded into
//   MFMA C-operand; 4x2-deep MFMA chains.

#define B_  64
#define T_  2048
#define E_  256
#define H_  256
#define O_  16
#define H2_ 128
#define CH  16    // chains per WG
#define HP  264   // padded per-chain h stride in halves (528 B)

typedef _Float16 f16x4 __attribute__((ext_vector_type(4)));
typedef _Float16 f16x8 __attribute__((ext_vector_type(8)));
typedef float    f32x4 __attribute__((ext_vector_type(4)));

// Workgroup barrier WITHOUT the vmcnt(0) drain __syncthreads() implies.
// Safe: inter-wave communication in the scan loop is via LDS only.
#define LDS_BARRIER() asm volatile("s_waitcnt lgkmcnt(0)\n\ts_barrier" ::: "memory")

__device__ __forceinline__ float tanh_fast(float x) {
  // tanh(x) = 1 - 2/(exp(2x)+1); exact at +/-inf
  const float e = __expf(2.0f * x);
  return fmaf(-2.0f, __builtin_amdgcn_rcpf(e + 1.0f), 1.0f);
}

// ---------------------------------------------------------------------------
// K1: gathered GEMM via MFMA. Grid = B*T/64 WGs x 256 thr (4 waves).
// ---------------------------------------------------------------------------
__global__ __launch_bounds__(256) void k1_xh(
    const int* __restrict__ x, const float* __restrict__ emb,
    const float* __restrict__ W_ih, const float* __restrict__ b_ih,
    const float* __restrict__ b_hh, _Float16* __restrict__ xh) {
  __shared__ _Float16 A16[64][264];   // A tile, then reused as C tile
  const int tid  = threadIdx.x;
  const int w    = tid >> 6;
  const int lane = tid & 63;
  const int nl   = lane & 15;
  const int koff = (lane >> 4) << 3;
  const long r0  = (long)blockIdx.x * 64;

  {  // stage 64 gathered emb rows -> fp16 LDS
    const int c4 = lane << 2;
#pragma unroll
    for (int it = 0; it < 16; ++it) {
      const int row = (it << 2) + w;
      const long tok = x[r0 + row];
      const float4 v = *(const float4*)&emb[tok * E_ + c4];
      f16x4 hv;
      hv[0] = (_Float16)v.x; hv[1] = (_Float16)v.y;
      hv[2] = (_Float16)v.z; hv[3] = (_Float16)v.w;
      *(f16x4*)&A16[row][c4] = hv;
    }
  }

  // B-fragments: W_ih rows n = 64w + 16nt + nl
  f16x8 bfr[4][8];
#pragma unroll
  for (int nt = 0; nt < 4; ++nt) {
    const int n = (w << 6) + (nt << 4) + nl;
#pragma unroll
    for (int kt = 0; kt < 8; ++kt) {
      const int k0 = (kt << 5) + koff;
      const float4 u0 = *(const float4*)&W_ih[n * E_ + k0];
      const float4 u1 = *(const float4*)&W_ih[n * E_ + k0 + 4];
      f16x8 bv;
      bv[0] = (_Float16)u0.x; bv[1] = (_Float16)u0.y;
      bv[2] = (_Float16)u0.z; bv[3] = (_Float16)u0.w;
      bv[4] = (_Float16)u1.x; bv[5] = (_Float16)u1.y;
      bv[6] = (_Float16)u1.z; bv[7] = (_Float16)u1.w;
      bfr[nt][kt] = bv;
    }
  }
  __syncthreads();

  f32x4 acc[4][4];
#pragma unroll
  for (int mt = 0; mt < 4; ++mt)
#pragma unroll
    for (int nt = 0; nt < 4; ++nt) acc[mt][nt] = (f32x4){};

#pragma unroll
  for (int mt = 0; mt < 4; ++mt) {
#pragma unroll
    for (int kt = 0; kt < 8; ++kt) {
      const f16x8 a = *(const f16x8*)&A16[(mt << 4) + nl][(kt << 5) + koff];
#pragma unroll
      for (int nt = 0; nt < 4; ++nt)
        acc[mt][nt] = __builtin_amdgcn_mfma_f32_16x16x32_f16(a, bfr[nt][kt], acc[mt][nt], 0, 0, 0);
    }
  }
  __syncthreads();  // done reading A16; reuse it for C

  {  // C -> LDS (fp16, +bias)
    const int rsub = (lane >> 4) << 2;
#pragma unroll
    for (int nt = 0; nt < 4; ++nt) {
      const int n = (w << 6) + (nt << 4) + nl;
      const float bias = b_ih[n] + b_hh[n];
#pragma unroll
      for (int mt = 0; mt < 4; ++mt)
#pragma unroll
        for (int j = 0; j < 4; ++j)
          A16[(mt << 4) + rsub + j][n] = (_Float16)(acc[mt][nt][j] + bias);
    }
  }
  __syncthreads();

  {  // coalesced 16B stores: wave w covers rows 16w..16w+15, 1KB/instr
#pragma unroll
    for (int i = 0; i < 8; ++i) {
      const int row = (w << 4) + (i << 1) + (lane >> 5);
      const int col = (lane & 31) << 3;
      *(f16x8*)&xh[(r0 + row) * H_ + col] = *(const f16x8*)&A16[row][col];
    }
  }
}

// ---------------------------------------------------------------------------
// K2: 16-chain batched scan. chain = nl = lane&15; C rows rb..rb+3 (mt=0)
// and rb+16..+19 (mt=1), rb = 32w + 4*quad.
// ---------------------------------------------------------------------------
__global__ __launch_bounds__(512, 1) void k2_rnn(
    const _Float16* __restrict__ xh, const float* __restrict__ W_hh,
    const float* __restrict__ fc1_w, const float* __restrict__ fc1_b,
    const float* __restrict__ fc2_w, const float* __restrict__ fc2_b,
    float* __restrict__ out) {
  __shared__ _Float16 h16[2][CH][HP];
  __shared__ float hid_s[CH][H2_ + 4];

  const int tid  = threadIdx.x;
  const int w    = tid >> 6;
  const int lane = tid & 63;
  const int nl   = lane & 15;
  const int quad = lane >> 4;
  const int koff = quad << 3;
  const int rb   = (w << 5) + (quad << 2);
  const int c0   = blockIdx.x * CH;

  // A-fragments: W_hh rows [32w,32w+32), fp32->fp16, loaded once
  f16x8 afr[2][8];
#pragma unroll
  for (int mt = 0; mt < 2; ++mt) {
    const int i = (w << 5) + (mt << 4) + nl;
#pragma unroll
    for (int kt = 0; kt < 8; ++kt) {
      const int k0 = (kt << 5) + koff;
      const float4 u0 = *(const float4*)&W_hh[i * H_ + k0];
      const float4 u1 = *(const float4*)&W_hh[i * H_ + k0 + 4];
      f16x8 av;
      av[0] = (_Float16)u0.x; av[1] = (_Float16)u0.y;
      av[2] = (_Float16)u0.z; av[3] = (_Float16)u0.w;
      av[4] = (_Float16)u1.x; av[5] = (_Float16)u1.y;
      av[6] = (_Float16)u1.z; av[7] = (_Float16)u1.w;
      afr[mt][kt] = av;
    }
  }

  // h0 = 0
  { *(f16x8*)&h16[0][tid >> 5][(tid & 31) << 3] = (f16x8){}; }

  // xh pointer for this lane: chain c0+nl, rows rb / rb+16
  const _Float16* xb = xh + (size_t)(c0 + nl) * (T_ * H_) + rb;

  // preload x[0..3] into 4 slot pairs (prefetch distance 4)
  f16x4 xs0a = *(const f16x4*)&xb[0 * H_], xs0b = *(const f16x4*)&xb[0 * H_ + 16];
  f16x4 xs1a = *(const f16x4*)&xb[1 * H_], xs1b = *(const f16x4*)&xb[1 * H_ + 16];
  f16x4 xs2a = *(const f16x4*)&xb[2 * H_], xs2b = *(const f16x4*)&xb[2 * H_ + 16];
  f16x4 xs3a = *(const f16x4*)&xb[3 * H_], xs3b = *(const f16x4*)&xb[3 * H_ + 16];
  __syncthreads();  // full barrier once before the loop

#define STEP(RB, WB, XA, XB, PT)                                               \
  {                                                                            \
    const size_t pp = (size_t)((PT) & (T_ - 1)) * H_;                          \
    f16x4 npa = *(const f16x4*)&xb[pp];                                        \
    f16x4 npb = *(const f16x4*)&xb[pp + 16];                                   \
    f16x8 bfr[8];                                                              \
    _Pragma("unroll")                                                          \
    for (int kt = 0; kt < 8; ++kt)                                             \
      bfr[kt] = *(const f16x8*)&h16[RB][nl][(kt << 5) + koff];                 \
    f32x4 xc0, xc1;                                                            \
    _Pragma("unroll")                                                          \
    for (int j = 0; j < 4; ++j) {                                              \
      xc0[j] = (float)XA[j]; xc1[j] = (float)XB[j];                            \
    }                                                                          \
    const f32x4 zz = {};                                                       \
    f32x4 a00 = __builtin_amdgcn_mfma_f32_16x16x32_f16(afr[0][0], bfr[0], xc0, 0, 0, 0); \
    a00       = __builtin_amdgcn_mfma_f32_16x16x32_f16(afr[0][1], bfr[1], a00, 0, 0, 0); \
    f32x4 a01 = __builtin_amdgcn_mfma_f32_16x16x32_f16(afr[0][2], bfr[2], zz,  0, 0, 0); \
    a01       = __builtin_amdgcn_mfma_f32_16x16x32_f16(afr[0][3], bfr[3], a01, 0, 0, 0); \
    f32x4 a02 = __builtin_amdgcn_mfma_f32_16x16x32_f16(afr[0][4], bfr[4], zz,  0, 0, 0); \
    a02       = __builtin_amdgcn_mfma_f32_16x16x32_f16(afr[0][5], bfr[5], a02, 0, 0, 0); \
    f32x4 a03 = __builtin_amdgcn_mfma_f32_16x16x32_f16(afr[0][6], bfr[6], zz,  0, 0, 0); \
    a03       = __builtin_amdgcn_mfma_f32_16x16x32_f16(afr[0][7], bfr[7], a03, 0, 0, 0); \
    f32x4 a10 = __builtin_amdgcn_mfma_f32_16x16x32_f16(afr[1][0], bfr[0], xc1, 0, 0, 0); \
    a10       = __builtin_amdgcn_mfma_f32_16x16x32_f16(afr[1][1], bfr[1], a10, 0, 0, 0); \
    f32x4 a11 = __builtin_amdgcn_mfma_f32_16x16x32_f16(afr[1][2], bfr[2], zz,  0, 0, 0); \
    a11       = __builtin_amdgcn_mfma_f32_16x16x32_f16(afr[1][3], bfr[3], a11, 0, 0, 0); \
    f32x4 a12 = __builtin_amdgcn_mfma_f32_16x16x32_f16(afr[1][4], bfr[4], zz,  0, 0, 0); \
    a12       = __builtin_amdgcn_mfma_f32_16x16x32_f16(afr[1][5], bfr[5], a12, 0, 0, 0); \
    f32x4 a13 = __builtin_amdgcn_mfma_f32_16x16x32_f16(afr[1][6], bfr[6], zz,  0, 0, 0); \
    a13       = __builtin_amdgcn_mfma_f32_16x16x32_f16(afr[1][7], bfr[7], a13, 0, 0, 0); \
    const f32x4 s0 = (a00 + a01) + (a02 + a03);                                \
    const f32x4 s1 = (a10 + a11) + (a12 + a13);                                \
    f16x4 o0, o1;                                                              \
    _Pragma("unroll")                                                          \
    for (int j = 0; j < 4; ++j) {                                              \
      o0[j] = (_Float16)tanh_fast(s0[j]);                                      \
      o1[j] = (_Float16)tanh_fast(s1[j]);                                      \
    }                                                                          \
    *(f16x4*)&h16[WB][nl][rb]      = o0;                                       \
    *(f16x4*)&h16[WB][nl][rb + 16] = o1;                                       \
    XA = npa; XB = npb;                                                        \
    LDS_BARRIER();                                                             \
  }

  for (int t = 0; t < T_; t += 4) {
    STEP(0, 1, xs0a, xs0b, t + 4)
    STEP(1, 0, xs1a, xs1b, t + 5)
    STEP(0, 1, xs2a, xs2b, t + 6)
    STEP(1, 0, xs3a, xs3b, t + 7)
  }
#undef STEP

  __syncthreads();  // full barrier before epilogue (drain everything once)

  // MLP head; final h in h16[0] (t=2047 writes buffer 0)
#pragma unroll
  for (int p = 0; p < 4; ++p) {
    const int c = (tid >> 7) + (p << 2);
    const int o = tid & 127;
    float s = fc1_b[o];
#pragma unroll 8
    for (int k = 0; k < H_; ++k) s += fc1_w[o * H_ + k] * (float)h16[0][c][k];
    hid_s[c][o] = fmaxf(s, 0.f);
  }
  __syncthreads();
  if (tid < CH * O_) {
    const int c = tid >> 4, o = tid & 15;
    float s = fc2_b[o];
#pragma unroll 8
    for (int k = 0; k < H2_; ++k) s += fc2_w[o * H2_ + k] * hid_s[c][k];
    out[(size_t)(c0 + c) * O_ + o] = s;
  }
}

extern "C" void kernel_launch(void* const* d_in, const int* in_sizes, int n_in,
                              void* d_out, int out_size, void* d_ws, size_t ws_size,
                              hipStream_t stream) {
  const int*   x     = (const int*)d_in[0];
  const float* emb   = (const float*)d_in[1];
  const float* W_ih  = (const float*)d_in[2];
  const float* W_hh  = (const float*)d_in[3];
  const float* b_ih  = (const float*)d_in[4];
  const float* b_hh  = (const float*)d_in[5];
  const float* fc1_w = (const float*)d_in[6];
  const float* fc1_b = (const float*)d_in[7];
  const float* fc2_w = (const float*)d_in[8];
  const float* fc2_b = (const float*)d_in[9];
  float* outp = (float*)d_out;

  _Float16* xh16 = (_Float16*)d_ws;  // 64 MiB

  k1_xh<<<dim3(B_ * T_ / 64), dim3(256), 0, stream>>>(x, emb, W_ih, b_ih, b_hh, xh16);
  k2_rnn<<<dim3(B_ / CH), dim3(512), 0, stream>>>(xh16, W_hh, fc1_w, fc1_b, fc2_w, fc2_b, outp);
}

// Round 5
// 1746.407 us; speedup vs baseline: 1.2514x; 1.0133x over previous
//
#include <hip/hip_runtime.h>
#include <hip/hip_bf16.h>

// RNNClassifier: B=64, T=2048, V=50000, E=256, H=256, O=16
// K0: convert W_ih, W_hh fp32 -> fp16 into d_ws (amortizes k1/k2 loads).
// K1 (MFMA f16): xh16[B*T][H] = fp16( emb[x] @ W_ih^T + b_ih + b_hh ).
// K2 (MFMA f16): 16 chains batched into B-columns; 4 WGs x **4 waves**;
//   wave w owns rows [64w,64w+64) (4 M-tiles), A-frags 128 VGPR/lane.
//   LDS B-reads halve vs R4 (32KB/step/CU): K2 was LDS-read-BW bound.
//   lgkmcnt-only barrier, xh prefetch distance 4, xh folded into MFMA C.

#define B_  64
#define T_  2048
#define E_  256
#define H_  256
#define O_  16
#define H2_ 128
#define CH  16    // chains per WG
#define HP  264   // padded per-chain h stride in halves (528 B, 16B-aligned)

typedef _Float16 f16x4 __attribute__((ext_vector_type(4)));
typedef _Float16 f16x8 __attribute__((ext_vector_type(8)));
typedef float    f32x4 __attribute__((ext_vector_type(4)));

// Barrier without the vmcnt(0) drain __syncthreads() implies.
// Safe: in-loop inter-wave communication is via LDS only.
#define LDS_BARRIER() asm volatile("s_waitcnt lgkmcnt(0)\n\ts_barrier" ::: "memory")

__device__ __forceinline__ float tanh_fast(float x) {
  const float e = __expf(2.0f * x);
  return fmaf(-2.0f, __builtin_amdgcn_rcpf(e + 1.0f), 1.0f);
}

// ---------------------------------------------------------------------------
// K0: W (fp32) -> fp16, 2*65536 elems.
// ---------------------------------------------------------------------------
__global__ __launch_bounds__(256) void k0_cvt(
    const float* __restrict__ W_ih, const float* __restrict__ W_hh,
    _Float16* __restrict__ Wih16, _Float16* __restrict__ Whh16) {
  const int i = (blockIdx.x * 256 + threadIdx.x) * 4;
  if (i < H_ * E_) {
    float4 a = *(const float4*)&W_ih[i];
    float4 b = *(const float4*)&W_hh[i];
    f16x4 ah, bh;
    ah[0]=(_Float16)a.x; ah[1]=(_Float16)a.y; ah[2]=(_Float16)a.z; ah[3]=(_Float16)a.w;
    bh[0]=(_Float16)b.x; bh[1]=(_Float16)b.y; bh[2]=(_Float16)b.z; bh[3]=(_Float16)b.w;
    *(f16x4*)&Wih16[i] = ah;
    *(f16x4*)&Whh16[i] = bh;
  }
}

// ---------------------------------------------------------------------------
// K1: gathered GEMM via MFMA. Grid = B*T/64 WGs x 256 thr (4 waves).
// ---------------------------------------------------------------------------
__global__ __launch_bounds__(256) void k1_xh(
    const int* __restrict__ x, const float* __restrict__ emb,
    const _Float16* __restrict__ Wih16, const float* __restrict__ b_ih,
    const float* __restrict__ b_hh, _Float16* __restrict__ xh) {
  __shared__ _Float16 A16[64][264];   // A tile, then reused as C tile
  const int tid  = threadIdx.x;
  const int w    = tid >> 6;
  const int lane = tid & 63;
  const int nl   = lane & 15;
  const int koff = (lane >> 4) << 3;
  const long r0  = (long)blockIdx.x * 64;

  {  // stage 64 gathered emb rows -> fp16 LDS
    const int c4 = lane << 2;
#pragma unroll
    for (int it = 0; it < 16; ++it) {
      const int row = (it << 2) + w;
      const long tok = x[r0 + row];
      const float4 v = *(const float4*)&emb[tok * E_ + c4];
      f16x4 hv;
      hv[0] = (_Float16)v.x; hv[1] = (_Float16)v.y;
      hv[2] = (_Float16)v.z; hv[3] = (_Float16)v.w;
      *(f16x4*)&A16[row][c4] = hv;
    }
  }

  // B-fragments: W_ih rows n = 64w + 16nt + nl (fp16 direct, 16B loads)
  f16x8 bfr[4][8];
#pragma unroll
  for (int nt = 0; nt < 4; ++nt) {
    const int n = (w << 6) + (nt << 4) + nl;
#pragma unroll
    for (int kt = 0; kt < 8; ++kt)
      bfr[nt][kt] = *(const f16x8*)&Wih16[n * E_ + (kt << 5) + koff];
  }
  __syncthreads();

  f32x4 acc[4][4];
#pragma unroll
  for (int mt = 0; mt < 4; ++mt)
#pragma unroll
    for (int nt = 0; nt < 4; ++nt) acc[mt][nt] = (f32x4){};

#pragma unroll
  for (int mt = 0; mt < 4; ++mt) {
#pragma unroll
    for (int kt = 0; kt < 8; ++kt) {
      const f16x8 a = *(const f16x8*)&A16[(mt << 4) + nl][(kt << 5) + koff];
#pragma unroll
      for (int nt = 0; nt < 4; ++nt)
        acc[mt][nt] = __builtin_amdgcn_mfma_f32_16x16x32_f16(a, bfr[nt][kt], acc[mt][nt], 0, 0, 0);
    }
  }
  __syncthreads();  // done reading A16; reuse as C tile

  {  // C -> LDS (fp16, +bias)
    const int rsub = (lane >> 4) << 2;
#pragma unroll
    for (int nt = 0; nt < 4; ++nt) {
      const int n = (w << 6) + (nt << 4) + nl;
      const float bias = b_ih[n] + b_hh[n];
#pragma unroll
      for (int mt = 0; mt < 4; ++mt)
#pragma unroll
        for (int j = 0; j < 4; ++j)
          A16[(mt << 4) + rsub + j][n] = (_Float16)(acc[mt][nt][j] + bias);
    }
  }
  __syncthreads();

  {  // coalesced 16B stores
#pragma unroll
    for (int i = 0; i < 8; ++i) {
      const int row = (w << 4) + (i << 1) + (lane >> 5);
      const int col = (lane & 31) << 3;
      *(f16x8*)&xh[(r0 + row) * H_ + col] = *(const f16x8*)&A16[row][col];
    }
  }
}

// ---------------------------------------------------------------------------
// K2: 16-chain batched scan, 4 waves. chain = nl; wave w owns rows
// [64w,64w+64) = 4 M-tiles; C rows (w<<6)+(mt<<4)+4*quad+j, col nl.
// ---------------------------------------------------------------------------
__global__ __launch_bounds__(256, 1) void k2_rnn(
    const _Float16* __restrict__ xh, const _Float16* __restrict__ Whh16,
    const float* __restrict__ fc1_w, const float* __restrict__ fc1_b,
    const float* __restrict__ fc2_w, const float* __restrict__ fc2_b,
    float* __restrict__ out) {
  __shared__ _Float16 h16[2][CH][HP];
  __shared__ float hid_s[CH][H2_ + 4];

  const int tid  = threadIdx.x;
  const int w    = tid >> 6;               // wave 0..3
  const int lane = tid & 63;
  const int nl   = lane & 15;              // chain / A-row-low
  const int quad = lane >> 4;
  const int koff = quad << 3;
  const int c0   = blockIdx.x * CH;

  // A-fragments: W_hh rows 64w+16mt+nl (fp16 direct), 128 VGPRs
  f16x8 afr[4][8];
#pragma unroll
  for (int mt = 0; mt < 4; ++mt) {
    const int i = (w << 6) + (mt << 4) + nl;
#pragma unroll
    for (int kt = 0; kt < 8; ++kt)
      afr[mt][kt] = *(const f16x8*)&Whh16[i * H_ + (kt << 5) + koff];
  }

  // h0 = 0 (256 thr x 16 halves = 4096)
  {
    const int c = tid >> 4, o = (tid & 15) << 4;
    *(f16x8*)&h16[0][c][o] = (f16x8){};
    *(f16x8*)&h16[0][c][o + 8] = (f16x8){};
  }

  // xh pointer: chain c0+nl; per-mt row offset (w<<6)+(mt<<4)+(quad<<2)
  const _Float16* xb = xh + (size_t)(c0 + nl) * (T_ * H_) + (w << 6) + (quad << 2);

  // prefetch slots for t=0..3 (distance 4)
  f16x4 xs[4][4];
#pragma unroll
  for (int s = 0; s < 4; ++s)
#pragma unroll
    for (int mt = 0; mt < 4; ++mt)
      xs[s][mt] = *(const f16x4*)&xb[(size_t)s * H_ + (mt << 4)];
  __syncthreads();

#define STEP(RB, WB, S, PT)                                                    \
  {                                                                            \
    const size_t pp = (size_t)((PT) & (T_ - 1)) * H_;                          \
    f16x4 np[4];                                                               \
    _Pragma("unroll")                                                          \
    for (int mt = 0; mt < 4; ++mt) np[mt] = *(const f16x4*)&xb[pp + (mt << 4)];\
    f16x8 bfr[8];                                                              \
    _Pragma("unroll")                                                          \
    for (int kt = 0; kt < 8; ++kt)                                             \
      bfr[kt] = *(const f16x8*)&h16[RB][nl][(kt << 5) + koff];                 \
    const f32x4 zz = {};                                                       \
    _Pragma("unroll")                                                          \
    for (int mt = 0; mt < 4; ++mt) {                                           \
      f32x4 xc;                                                                \
      _Pragma("unroll")                                                        \
      for (int j = 0; j < 4; ++j) xc[j] = (float)xs[S][mt][j];                 \
      f32x4 alo = __builtin_amdgcn_mfma_f32_16x16x32_f16(afr[mt][0], bfr[0], xc, 0, 0, 0); \
      alo       = __builtin_amdgcn_mfma_f32_16x16x32_f16(afr[mt][1], bfr[1], alo, 0, 0, 0); \
      alo       = __builtin_amdgcn_mfma_f32_16x16x32_f16(afr[mt][2], bfr[2], alo, 0, 0, 0); \
      alo       = __builtin_amdgcn_mfma_f32_16x16x32_f16(afr[mt][3], bfr[3], alo, 0, 0, 0); \
      f32x4 ahi = __builtin_amdgcn_mfma_f32_16x16x32_f16(afr[mt][4], bfr[4], zz, 0, 0, 0);  \
      ahi       = __builtin_amdgcn_mfma_f32_16x16x32_f16(afr[mt][5], bfr[5], ahi, 0, 0, 0); \
      ahi       = __builtin_amdgcn_mfma_f32_16x16x32_f16(afr[mt][6], bfr[6], ahi, 0, 0, 0); \
      ahi       = __builtin_amdgcn_mfma_f32_16x16x32_f16(afr[mt][7], bfr[7], ahi, 0, 0, 0); \
      const f32x4 s2 = alo + ahi;                                              \
      f16x4 o;                                                                 \
      _Pragma("unroll")                                                        \
      for (int j = 0; j < 4; ++j) o[j] = (_Float16)tanh_fast(s2[j]);           \
      *(f16x4*)&h16[WB][nl][(w << 6) + (mt << 4) + (quad << 2)] = o;           \
      xs[S][mt] = np[mt];                                                      \
    }                                                                          \
    LDS_BARRIER();                                                             \
  }

  for (int t = 0; t < T_; t += 4) {
    STEP(0, 1, 0, t + 4)
    STEP(1, 0, 1, t + 5)
    STEP(0, 1, 2, t + 6)
    STEP(1, 0, 3, t + 7)
  }
#undef STEP

  __syncthreads();  // drain everything once before epilogue

  // MLP head; final h in h16[0] (T even)
#pragma unroll
  for (int p = 0; p < 8; ++p) {
    const int c = (tid >> 7) + (p << 1);
    const int o = tid & 127;
    float s = fc1_b[o];
#pragma unroll 8
    for (int k = 0; k < H_; ++k) s += fc1_w[o * H_ + k] * (float)h16[0][c][k];
    hid_s[c][o] = fmaxf(s, 0.f);
  }
  __syncthreads();
  {
    const int c = tid >> 4, o = tid & 15;
    float s = fc2_b[o];
#pragma unroll 8
    for (int k = 0; k < H2_; ++k) s += fc2_w[o * H2_ + k] * hid_s[c][k];
    out[(size_t)(c0 + c) * O_ + o] = s;
  }
}

extern "C" void kernel_launch(void* const* d_in, const int* in_sizes, int n_in,
                              void* d_out, int out_size, void* d_ws, size_t ws_size,
                              hipStream_t stream) {
  const int*   x     = (const int*)d_in[0];
  const float* emb   = (const float*)d_in[1];
  const float* W_ih  = (const float*)d_in[2];
  const float* W_hh  = (const float*)d_in[3];
  const float* b_ih  = (const float*)d_in[4];
  const float* b_hh  = (const float*)d_in[5];
  const float* fc1_w = (const float*)d_in[6];
  const float* fc1_b = (const float*)d_in[7];
  const float* fc2_w = (const float*)d_in[8];
  const float* fc2_b = (const float*)d_in[9];
  float* outp = (float*)d_out;

  _Float16* xh16  = (_Float16*)d_ws;                    // 64 MiB
  _Float16* Wih16 = xh16 + (size_t)B_ * T_ * H_;        // 128 KiB
  _Float16* Whh16 = Wih16 + (size_t)H_ * E_;            // 128 KiB

  k0_cvt<<<dim3((H_ * E_ / 4 + 255) / 256), dim3(256), 0, stream>>>(W_ih, W_hh, Wih16, Whh16);
  k1_xh<<<dim3(B_ * T_ / 64), dim3(256), 0, stream>>>(x, emb, Wih16, b_ih, b_hh, xh16);
  k2_rnn<<<dim3(B_ / CH), dim3(256), 0, stream>>>(xh16, Whh16, fc1_w, fc1_b, fc2_w, fc2_b, outp);
}

// Round 6
// 1634.541 us; speedup vs baseline: 1.3370x; 1.0684x over previous
//
#include <hip/hip_runtime.h>
#include <hip/hip_bf16.h>

// RNNClassifier: B=64, T=2048, V=50000, E=256, H=256, O=16
// K0: W_ih/W_hh fp32 -> fp16 once into d_ws.
// K1 (MFMA f16): xh16[B*T][H] = fp16( emb[x] @ W_ih^T + b_ih + b_hh ).
// K2 (MFMA f16): scan. 16 WGs x 4 chains x 4 waves. Per step:
//   phase1: wave w rows [64w,64w+64): 32 MFMA, f32 sums -> LDS scratch
//   phase2: all 256 thr: 4 tanh each (sums + xh), write h16[nxt]
//   Two lgkmcnt-only barriers/step (no vmcnt drain); xh via chunk-4
//   register relay (loads consumed one full chunk after issue).

#define B_  64
#define T_  2048
#define E_  256
#define H_  256
#define O_  16
#define H2_ 128
#define CH  4     // chains per WG
#define HP  264   // padded h stride (halves)

typedef _Float16 f16x4 __attribute__((ext_vector_type(4)));
typedef _Float16 f16x8 __attribute__((ext_vector_type(8)));
typedef float    f32x4 __attribute__((ext_vector_type(4)));

// Barrier without __syncthreads()'s vmcnt(0) drain. Safe: in-loop cross-wave
// communication is LDS-only.
#define LDS_BARRIER() asm volatile("s_waitcnt lgkmcnt(0)\n\ts_barrier" ::: "memory")

__device__ __forceinline__ float tanh_fast(float x) {
  const float e = __expf(2.0f * x);
  return fmaf(-2.0f, __builtin_amdgcn_rcpf(e + 1.0f), 1.0f);
}

// ---------------------------------------------------------------------------
__global__ __launch_bounds__(256) void k0_cvt(
    const float* __restrict__ W_ih, const float* __restrict__ W_hh,
    _Float16* __restrict__ Wih16, _Float16* __restrict__ Whh16) {
  const int i = (blockIdx.x * 256 + threadIdx.x) * 4;
  if (i < H_ * E_) {
    float4 a = *(const float4*)&W_ih[i];
    float4 b = *(const float4*)&W_hh[i];
    f16x4 ah, bh;
    ah[0]=(_Float16)a.x; ah[1]=(_Float16)a.y; ah[2]=(_Float16)a.z; ah[3]=(_Float16)a.w;
    bh[0]=(_Float16)b.x; bh[1]=(_Float16)b.y; bh[2]=(_Float16)b.z; bh[3]=(_Float16)b.w;
    *(f16x4*)&Wih16[i] = ah;
    *(f16x4*)&Whh16[i] = bh;
  }
}

// ---------------------------------------------------------------------------
// K1: gathered GEMM via MFMA (unchanged from R5).
// ---------------------------------------------------------------------------
__global__ __launch_bounds__(256) void k1_xh(
    const int* __restrict__ x, const float* __restrict__ emb,
    const _Float16* __restrict__ Wih16, const float* __restrict__ b_ih,
    const float* __restrict__ b_hh, _Float16* __restrict__ xh) {
  __shared__ _Float16 A16[64][264];
  const int tid  = threadIdx.x;
  const int w    = tid >> 6;
  const int lane = tid & 63;
  const int nl   = lane & 15;
  const int koff = (lane >> 4) << 3;
  const long r0  = (long)blockIdx.x * 64;

  {
    const int c4 = lane << 2;
#pragma unroll
    for (int it = 0; it < 16; ++it) {
      const int row = (it << 2) + w;
      const long tok = x[r0 + row];
      const float4 v = *(const float4*)&emb[tok * E_ + c4];
      f16x4 hv;
      hv[0] = (_Float16)v.x; hv[1] = (_Float16)v.y;
      hv[2] = (_Float16)v.z; hv[3] = (_Float16)v.w;
      *(f16x4*)&A16[row][c4] = hv;
    }
  }

  f16x8 bfr[4][8];
#pragma unroll
  for (int nt = 0; nt < 4; ++nt) {
    const int n = (w << 6) + (nt << 4) + nl;
#pragma unroll
    for (int kt = 0; kt < 8; ++kt)
      bfr[nt][kt] = *(const f16x8*)&Wih16[n * E_ + (kt << 5) + koff];
  }
  __syncthreads();

  f32x4 acc[4][4];
#pragma unroll
  for (int mt = 0; mt < 4; ++mt)
#pragma unroll
    for (int nt = 0; nt < 4; ++nt) acc[mt][nt] = (f32x4){};

#pragma unroll
  for (int mt = 0; mt < 4; ++mt) {
#pragma unroll
    for (int kt = 0; kt < 8; ++kt) {
      const f16x8 a = *(const f16x8*)&A16[(mt << 4) + nl][(kt << 5) + koff];
#pragma unroll
      for (int nt = 0; nt < 4; ++nt)
        acc[mt][nt] = __builtin_amdgcn_mfma_f32_16x16x32_f16(a, bfr[nt][kt], acc[mt][nt], 0, 0, 0);
    }
  }
  __syncthreads();

  {
    const int rsub = (lane >> 4) << 2;
#pragma unroll
    for (int nt = 0; nt < 4; ++nt) {
      const int n = (w << 6) + (nt << 4) + nl;
      const float bias = b_ih[n] + b_hh[n];
#pragma unroll
      for (int mt = 0; mt < 4; ++mt)
#pragma unroll
        for (int j = 0; j < 4; ++j)
          A16[(mt << 4) + rsub + j][n] = (_Float16)(acc[mt][nt][j] + bias);
    }
  }
  __syncthreads();

  {
#pragma unroll
    for (int i = 0; i < 8; ++i) {
      const int row = (w << 4) + (i << 1) + (lane >> 5);
      const int col = (lane & 31) << 3;
      *(f16x8*)&xh[(r0 + row) * H_ + col] = *(const f16x8*)&A16[row][col];
    }
  }
}

// ---------------------------------------------------------------------------
// K2: 4-chain scan, 16 WGs x 256 thr. Wave w owns rows [64w,64w+64) in
// phase1 and chain w in phase2.
// ---------------------------------------------------------------------------
__global__ __launch_bounds__(256, 1) void k2_rnn(
    const _Float16* __restrict__ xh, const _Float16* __restrict__ Whh16,
    const float* __restrict__ fc1_w, const float* __restrict__ fc1_b,
    const float* __restrict__ fc2_w, const float* __restrict__ fc2_b,
    float* __restrict__ out) {
  __shared__ _Float16 h16[2][CH][HP];   // ping-pong hidden state (fp16)
  __shared__ float    sc[CH][264];      // f32 matvec sums scratch
  __shared__ float    hid_s[CH][H2_ + 4];

  const int tid  = threadIdx.x;
  const int w    = tid >> 6;            // wave 0..3
  const int lane = tid & 63;
  const int nl   = lane & 15;
  const int quad = lane >> 4;
  const int cc   = nl & 3;              // chain for B-frag (dedup broadcast)
  const int koff = quad << 3;
  const int c0   = blockIdx.x * CH;

  // A-frags: W_hh rows 64w+16mt+nl (fp16), 128 VGPRs
  f16x8 afr[4][8];
#pragma unroll
  for (int mt = 0; mt < 4; ++mt) {
    const int i = (w << 6) + (mt << 4) + nl;
#pragma unroll
    for (int kt = 0; kt < 8; ++kt)
      afr[mt][kt] = *(const f16x8*)&Whh16[i * H_ + (kt << 5) + koff];
  }

  // h0 = 0 (zero whole h16[0] incl pads: 4*264=1056 halves)
  if (tid < 132) *(f16x8*)&(((_Float16*)h16[0])[tid << 3]) = (f16x8){};

  // xh relay: wave w <-> chain c0+w; lane covers rows 4*lane..4*lane+3
  const _Float16* xb = xh + (size_t)(c0 + w) * T_ * H_ + (lane << 2);
  f16x4 xc[4], xn[4];
#pragma unroll
  for (int s = 0; s < 4; ++s) xc[s] = *(const f16x4*)&xb[(size_t)s * H_];
#pragma unroll
  for (int s = 0; s < 4; ++s) xn[s] = *(const f16x4*)&xb[(size_t)(4 + s) * H_];
  __syncthreads();  // one full barrier before the loop

#define STEP(RB, WB, S)                                                        \
  {                                                                            \
    f16x8 bfr[8];                                                              \
    _Pragma("unroll")                                                          \
    for (int kt = 0; kt < 8; ++kt)                                             \
      bfr[kt] = *(const f16x8*)&h16[RB][cc][(kt << 5) + koff];                 \
    const f32x4 zz = {};                                                       \
    f32x4 sum[4];                                                              \
    _Pragma("unroll")                                                          \
    for (int mt = 0; mt < 4; ++mt) {                                           \
      f32x4 alo = __builtin_amdgcn_mfma_f32_16x16x32_f16(afr[mt][0], bfr[0], zz, 0, 0, 0);  \
      alo       = __builtin_amdgcn_mfma_f32_16x16x32_f16(afr[mt][1], bfr[1], alo, 0, 0, 0); \
      alo       = __builtin_amdgcn_mfma_f32_16x16x32_f16(afr[mt][2], bfr[2], alo, 0, 0, 0); \
      alo       = __builtin_amdgcn_mfma_f32_16x16x32_f16(afr[mt][3], bfr[3], alo, 0, 0, 0); \
      f32x4 ahi = __builtin_amdgcn_mfma_f32_16x16x32_f16(afr[mt][4], bfr[4], zz, 0, 0, 0);  \
      ahi       = __builtin_amdgcn_mfma_f32_16x16x32_f16(afr[mt][5], bfr[5], ahi, 0, 0, 0); \
      ahi       = __builtin_amdgcn_mfma_f32_16x16x32_f16(afr[mt][6], bfr[6], ahi, 0, 0, 0); \
      ahi       = __builtin_amdgcn_mfma_f32_16x16x32_f16(afr[mt][7], bfr[7], ahi, 0, 0, 0); \
      sum[mt] = alo + ahi;                                                     \
    }                                                                          \
    if (nl < 4) {                                                              \
      _Pragma("unroll")                                                        \
      for (int mt = 0; mt < 4; ++mt)                                           \
        *(f32x4*)&sc[nl][(w << 6) + (mt << 4) + (quad << 2)] = sum[mt];        \
    }                                                                          \
    LDS_BARRIER();                                                             \
    {                                                                          \
      const f32x4 sv = *(const f32x4*)&sc[w][lane << 2];                       \
      f16x4 o;                                                                 \
      _Pragma("unroll")                                                        \
      for (int j = 0; j < 4; ++j)                                              \
        o[j] = (_Float16)tanh_fast(sv[j] + (float)xc[S][j]);                   \
      *(f16x4*)&h16[WB][w][lane << 2] = o;                                     \
    }                                                                          \
    LDS_BARRIER();                                                             \
  }

  for (int t = 0; t < T_; t += 4) {
    STEP(0, 1, 0)
    STEP(1, 0, 1)
    STEP(0, 1, 2)
    STEP(1, 0, 3)
    // chunk rotate: waits here for loads issued one full chunk ago
#pragma unroll
    for (int s = 0; s < 4; ++s) xc[s] = xn[s];
    const int tn = (t + 8) & (T_ - 1);  // wraps at tail; values unused
#pragma unroll
    for (int s = 0; s < 4; ++s) xn[s] = *(const f16x4*)&xb[(size_t)(tn + s) * H_];
  }
#undef STEP

  __syncthreads();  // full drain before epilogue

  // MLP head; final h in h16[0] (t=2047 writes buffer 0)
#pragma unroll
  for (int p = 0; p < 2; ++p) {
    const int c = (tid >> 7) + (p << 1);
    const int o = tid & 127;
    float s = fc1_b[o];
#pragma unroll 8
    for (int k = 0; k < H_; ++k) s += fc1_w[o * H_ + k] * (float)h16[0][c][k];
    hid_s[c][o] = fmaxf(s, 0.f);
  }
  __syncthreads();
  if (tid < CH * O_) {
    const int c = tid >> 4, o = tid & 15;
    float s = fc2_b[o];
#pragma unroll 8
    for (int k = 0; k < H2_; ++k) s += fc2_w[o * H2_ + k] * hid_s[c][k];
    out[(size_t)(c0 + c) * O_ + o] = s;
  }
}

extern "C" void kernel_launch(void* const* d_in, const int* in_sizes, int n_in,
                              void* d_out, int out_size, void* d_ws, size_t ws_size,
                              hipStream_t stream) {
  const int*   x     = (const int*)d_in[0];
  const float* emb   = (const float*)d_in[1];
  const float* W_ih  = (const float*)d_in[2];
  const float* W_hh  = (const float*)d_in[3];
  const float* b_ih  = (const float*)d_in[4];
  const float* b_hh  = (const float*)d_in[5];
  const float* fc1_w = (const float*)d_in[6];
  const float* fc1_b = (const float*)d_in[7];
  const float* fc2_w = (const float*)d_in[8];
  const float* fc2_b = (const float*)d_in[9];
  float* outp = (float*)d_out;

  _Float16* xh16  = (_Float16*)d_ws;                    // 64 MiB
  _Float16* Wih16 = xh16 + (size_t)B_ * T_ * H_;        // 128 KiB
  _Float16* Whh16 = Wih16 + (size_t)H_ * E_;            // 128 KiB

  k0_cvt<<<dim3(H_ * E_ / 1024), dim3(256), 0, stream>>>(W_ih, W_hh, Wih16, Whh16);
  k1_xh<<<dim3(B_ * T_ / 64), dim3(256), 0, stream>>>(x, emb, Wih16, b_ih, b_hh, xh16);
  k2_rnn<<<dim3(B_ / CH), dim3(256), 0, stream>>>(xh16, Whh16, fc1_w, fc1_b, fc2_w, fc2_b, outp);
}